// Round 8
// baseline (154.502 us; speedup 1.0000x reference)
//
#include <hip/hip_runtime.h>

#define M_TOT 32768
#define K_TOT 768
#define N_TOT 768

typedef int v4i __attribute__((ext_vector_type(4)));

#define GLOAD_LDS(g, l) __builtin_amdgcn_global_load_lds( \
    (const __attribute__((address_space(1))) unsigned int*)(g), \
    (__attribute__((address_space(3))) unsigned int*)(l), 16, 0, 0)

// Pack 4 int32 (each holding an int8 value) into one dword of 4 bytes. (verified R2)
__device__ __forceinline__ unsigned pack4(v4i a) {
  unsigned lo = __builtin_amdgcn_perm((unsigned)a.y, (unsigned)a.x, 0x00000400u);
  unsigned hi = __builtin_amdgcn_perm((unsigned)a.w, (unsigned)a.z, 0x00000400u);
  return __builtin_amdgcn_perm(hi, lo, 0x05040100u);
}

// W[k][n] int32 -> W8T[n][k] int8 (transposed, packed)
__global__ __launch_bounds__(256) void pack_w_kernel(const int* __restrict__ W,
                                                     signed char* __restrict__ W8T) {
  __shared__ signed char t[64][72];
  const int k0 = blockIdx.x * 64, n0 = blockIdx.y * 64;
  for (int i = threadIdx.x; i < 4096; i += 256) {
    int k = i >> 6, n = i & 63;
    t[n][k] = (signed char)W[(k0 + k) * N_TOT + n0 + n];
  }
  __syncthreads();
  for (int i = threadIdx.x; i < 4096; i += 256) {
    int n = i >> 6, k = i & 63;
    W8T[(n0 + n) * K_TOT + k0 + k] = t[n][k];
  }
}

// out_i32 = clamp(round((X@W)*alpha + bias))
// BM=64, BN=64, BK=64; 256 thr = 4 waves, each wave owns a DISTINCT 16-row
// m-frag (wv) and all 64 cols (bf[4]).
// A: DIRECT global->register. Lane (fr,fg) needs row fr k-bytes [fg*16,+16)
//    = 16 consecutive int32 of X = 4 dwordx4 + 4 pack4 -> af. NO A-LDS.
// B: 4KB/step ring-4 LDS via gload_lds (1/thread/step), L2-hot W8T.
// Depth-3 pipeline: stage k+3 issued at iter k. FIFO ledger (5 vmem/stage,
// order [B,A,A,A,A]): steady TOP=vmcnt(10) drains stage k exactly, leaving
// stages k+1,k+2 in flight. Tail: iter10 vmcnt(5), iter11 vmcnt(0).
// One counted wait + one 4-wave barrier per iter; no mid-wait, no lgkm asm.
__global__ __launch_bounds__(256, 4) void gemm_i8_kernel(
    const int* __restrict__ X, const signed char* __restrict__ W8T,
    const float* __restrict__ bias, const float* __restrict__ alpha_p,
    int* __restrict__ out) {
  __shared__ __align__(16) signed char Bbuf[4][4096];

  // Bijective XCD-chunked swizzle: 6144 wgs = 8 XCDs x 768; nt fast so the 12
  // sibling N-tiles of one X M-panel (192KB) share that XCD's L2.
  const int d = blockIdx.x;
  const int t = (d & 7) * 768 + (d >> 3);
  const int mt = t / 12, nt = t - mt * 12;
  const int row0 = mt << 6, col0 = nt << 6;

  const int tid = threadIdx.x;
  const int lane = tid & 63;
  const int wv = tid >> 6;                 // 0..3 = m-frag row block
  const int fr = lane & 15, fg = lane >> 4;

  // A base: row (row0 + wv*16 + fr), int col fg*16. All loop loads are
  // immediate offsets (ks*256B + j*16B <= 2864 < 4095) off this one base.
  const int* Xrow = X + (row0 + wv * 16 + fr) * K_TOT + fg * 16;

  // B staging: thread -> chunk tid: row r = tid>>2, slot = tid&3; source
  // pre-swizzled so linear LDS dest + swizzled read agree (rule #21).
  const int bsrc = (col0 + (tid >> 2)) * K_TOT +
                   (((tid & 3) << 4) ^ (((tid >> 2) & 3) << 4));

  // bf read lane addr: row (n*16+fr) -> fr*64 + swz; n*1024 + ring*4096 imm.
  const int brd = fr * 64 + ((fg << 4) ^ ((fr & 3) << 4));

  v4i q[3][4];
  const v4i zero = {0, 0, 0, 0};
  v4i acc[4];
#pragma unroll
  for (int n = 0; n < 4; ++n) acc[n] = zero;

#define ISSUE_A(ks)                                                      \
  do {                                                                   \
    _Pragma("unroll") for (int j = 0; j < 4; ++j)                        \
        q[(ks) % 3][j] = *(const v4i*)(Xrow + (ks) * 64 + j * 4);        \
  } while (0)

#define ISSUE_B(ks)                                                      \
  GLOAD_LDS(W8T + (ks) * 64 + bsrc, &Bbuf[(ks) & 3][wv * 1024])

  // GITER: top-wait (stage ks fully retired: B in LDS, A in regs) -> barrier
  // -> pack af from q[ks%3] (frees ring slot) -> issue stage ks+3 -> ds_read
  // bf -> 4 MFMA. Barrier also fences Bbuf slot (ks+3)&3 = (ks-1)&3 reuse.
#define GITER(ks, TOPW, DO3)                                             \
  do {                                                                   \
    asm volatile("s_waitcnt vmcnt(" TOPW ")" ::: "memory");              \
    __builtin_amdgcn_s_barrier();                                        \
    v4i af;                                                              \
    af.x = (int)pack4(q[(ks) % 3][0]);                                   \
    af.y = (int)pack4(q[(ks) % 3][1]);                                   \
    af.z = (int)pack4(q[(ks) % 3][2]);                                   \
    af.w = (int)pack4(q[(ks) % 3][3]);                                   \
    if (DO3) { ISSUE_B((ks) + 3); ISSUE_A((ks) + 3); }                   \
    v4i bf[4];                                                           \
    _Pragma("unroll") for (int n = 0; n < 4; ++n)                        \
        bf[n] = *(const v4i*)&Bbuf[(ks) & 3][n * 1024 + brd];            \
    __builtin_amdgcn_s_setprio(1);                                       \
    _Pragma("unroll") for (int n = 0; n < 4; ++n)                        \
        acc[n] = __builtin_amdgcn_mfma_i32_16x16x64_i8(af, bf[n],        \
                                                       acc[n], 0, 0, 0); \
    __builtin_amdgcn_s_setprio(0);                                       \
  } while (0)

  // Prologue: stages 0,1,2 in flight ([B,A4] x3 = 15 vmem ops).
  ISSUE_B(0); ISSUE_A(0);
  ISSUE_B(1); ISSUE_A(1);
  ISSUE_B(2); ISSUE_A(2);

  GITER(0, "10", 1);
  GITER(1, "10", 1);
  GITER(2, "10", 1);
  GITER(3, "10", 1);
  GITER(4, "10", 1);
  GITER(5, "10", 1);
  GITER(6, "10", 1);
  GITER(7, "10", 1);
  GITER(8, "10", 1);   // issues stage 11 (last)
  GITER(9, "10", 0);   // outstanding 9,10,11 -> drain 9
  GITER(10, "5", 0);   // outstanding 10,11 -> drain 10
  GITER(11, "0", 0);

  // Epilogue: C/D layout col = lane&15, row = (lane>>4)*4 + reg. Output int32.
  const float alpha = *alpha_p;
  float bv[4];
#pragma unroll
  for (int n = 0; n < 4; ++n) bv[n] = bias[col0 + n * 16 + fr];

  const int orow0 = row0 + wv * 16 + fg * 4;
#pragma unroll
  for (int n = 0; n < 4; ++n) {
    int* po = out + orow0 * N_TOT + col0 + n * 16 + fr;
#pragma unroll
    for (int r = 0; r < 4; ++r) {
      float v = rintf((float)acc[n][r] * alpha + bv[n]);
      v = fminf(127.f, fmaxf(-128.f, v));
      po[r * N_TOT] = (int)v;
    }
  }
}

extern "C" void kernel_launch(void* const* d_in, const int* in_sizes, int n_in,
                              void* d_out, int out_size, void* d_ws, size_t ws_size,
                              hipStream_t stream) {
  const int* X = (const int*)d_in[0];        // [4,8192,768] int8 promoted to int32
  const int* W = (const int*)d_in[1];        // [768,768] int8 promoted to int32
  const float* bias = (const float*)d_in[2]; // [1,768] fp16 promoted to float32
  const float* alpha = (const float*)d_in[3];
  int* out = (int*)d_out;                    // int8 output promoted to int32
  signed char* W8T = (signed char*)d_ws;     // 768*768 = 589,824 B scratch

  dim3 pg(K_TOT / 64, N_TOT / 64);
  pack_w_kernel<<<pg, 256, 0, stream>>>(W, W8T);
  gemm_i8_kernel<<<(M_TOT / 64) * (N_TOT / 64), 256, 0, stream>>>(X, W8T, bias, alpha, out);
}

// Round 9
// 93.271 us; speedup vs baseline: 1.6565x; 1.6565x over previous
//
#include <hip/hip_runtime.h>

#define M_TOT 32768
#define K_TOT 768
#define N_TOT 768

typedef int v4i __attribute__((ext_vector_type(4)));

#define GLOAD_LDS(g, l) __builtin_amdgcn_global_load_lds( \
    (const __attribute__((address_space(1))) unsigned int*)(g), \
    (__attribute__((address_space(3))) unsigned int*)(l), 16, 0, 0)

// Pack 4 int32 (each holding an int8 value) into one dword of 4 bytes. (verified R2)
__device__ __forceinline__ unsigned pack4(v4i a) {
  unsigned lo = __builtin_amdgcn_perm((unsigned)a.y, (unsigned)a.x, 0x00000400u);
  unsigned hi = __builtin_amdgcn_perm((unsigned)a.w, (unsigned)a.z, 0x00000400u);
  return __builtin_amdgcn_perm(hi, lo, 0x05040100u);
}

// W[k][n] int32 -> W8T[n][k] int8 (transposed, packed)
__global__ __launch_bounds__(256) void pack_w_kernel(const int* __restrict__ W,
                                                     signed char* __restrict__ W8T) {
  __shared__ signed char t[64][72];
  const int k0 = blockIdx.x * 64, n0 = blockIdx.y * 64;
  for (int i = threadIdx.x; i < 4096; i += 256) {
    int k = i >> 6, n = i & 63;
    t[n][k] = (signed char)W[(k0 + k) * N_TOT + n0 + n];
  }
  __syncthreads();
  for (int i = threadIdx.x; i < 4096; i += 256) {
    int n = i >> 6, k = i & 63;
    W8T[(n0 + n) * K_TOT + k0 + k] = t[n][k];
  }
}

// out_i32 = clamp(round((X@W)*alpha + bias))
// BM=128, BN=128, BK=64; 256 thr = 4 waves stacked VERTICALLY (wave wv owns
// rows wv*32..+31, all 128 cols): wave tile 32x128 = 2 m-frags x 8 n-frags.
// A: DIRECT global->register, q[2][8] double-buffer, pack4 at consumption.
//    No A-LDS, no mid-wait, no ds_writes. Cover = 2.0 iters.
// B: gload_lds ring-3. LDS layout: 128B rows holding 2 cols each, 3-bit XOR
//    swizzle (R7-proven conflict-free geometry); source pre-swizzled (rule 21).
// FIFO ledger (stage = 8 A dwordx4 + 2 B gload_lds = 10 ops, issued k+2 at
// iter k): steady TOP=vmcnt(10) drains stage k exactly (leaves stage k+1);
// last iter vmcnt(0). ONE wait + ONE barrier per iter.
__global__ __launch_bounds__(256, 3) void gemm_i8_kernel(
    const int* __restrict__ X, const signed char* __restrict__ W8T,
    const float* __restrict__ bias, const float* __restrict__ alpha_p,
    int* __restrict__ out) {
  __shared__ __align__(16) signed char Bbuf[3][8192];

  // Bijective XCD-chunked swizzle: 1536 wgs = 8 XCDs x 192; nt fast so the 6
  // sibling N-tiles of one X M-panel share that XCD's L2.
  const int d = blockIdx.x;
  const int t = (d & 7) * 192 + (d >> 3);
  const int mt = t / 6, nt = t - mt * 6;
  const int row0 = mt << 7, col0 = nt << 7;

  const int tid = threadIdx.x;
  const int lane = tid & 63;
  const int wv = tid >> 6;                // 0..3 vertical wave block
  const int fr = lane & 15, fg = lane >> 4;

  // A bases: m-frag mm covers rows row0 + wv*32 + mm*16 + fr, k-bytes fg*16..+16
  // (as 16 int32 = 4 dwordx4). Loop offsets ks*256B + j*16B <= 2864B fit imm.
  const int* XrowM0 = X + (row0 + wv * 32 + fr) * K_TOT + fg * 16;
  const int* XrowM1 = XrowM0 + 16 * K_TOT;

  // B source pre-swizzle. LDS byte e = c*16 (chunk c = i*256+tid) holds:
  //   prow = c>>3, sl = (c&7) ^ (prow&7)  ->  col = col0 + 2*prow + (sl>>2),
  //   k-slot = sl&3. Then frag read applies the same XOR (involution).
  int bsrc[2];
#pragma unroll
  for (int i = 0; i < 2; ++i) {
    int c = i * 256 + tid;
    int prow = c >> 3;
    int sl = (c & 7) ^ (prow & 7);
    bsrc[i] = (col0 + 2 * prow + (sl >> 2)) * K_TOT + ((sl & 3) << 4);
  }
  const signed char* bptr0 = W8T + bsrc[0];
  const signed char* bptr1 = W8T + bsrc[1];
  const int bdst0 = wv * 1024;            // wave-uniform; HW adds lane*16
  const int bdst1 = 4096 + wv * 1024;

  // bf frag read: logical row r = n*16+fr -> prow = n*8 + (fr>>1); note
  // prow&7 == fr>>1 independent of n, so the per-lane base is n-invariant:
  const int p0 = fr >> 1;
  const int brd = p0 * 128 + (((((fr & 1) << 2) | fg) ^ p0) << 4);

  v4i q[2][8];
  const v4i zero = {0, 0, 0, 0};
  v4i acc[2][8];
#pragma unroll
  for (int m = 0; m < 2; ++m)
#pragma unroll
    for (int n = 0; n < 8; ++n) acc[m][n] = zero;

#define ISSUE_A(ks)                                                      \
  do {                                                                   \
    _Pragma("unroll") for (int j = 0; j < 4; ++j) {                      \
      q[(ks) & 1][j]     = *(const v4i*)(XrowM0 + (ks) * 64 + j * 4);    \
      q[(ks) & 1][4 + j] = *(const v4i*)(XrowM1 + (ks) * 64 + j * 4);    \
    }                                                                    \
  } while (0)

#define ISSUE_B(ks)                                                      \
  do {                                                                   \
    GLOAD_LDS(bptr0 + (ks) * 64, &Bbuf[(ks) % 3][bdst0]);                \
    GLOAD_LDS(bptr1 + (ks) * 64, &Bbuf[(ks) % 3][bdst1]);                \
  } while (0)

  // GITER: wait (stage ks fully retired: A in regs, B in LDS) -> barrier
  // (all waves' B(ks) visible; slot (ks+2)%3 free for reuse) -> pack af from
  // q[ks&1] -> issue stage ks+2 (A reuses just-consumed q slot) -> 8x
  // {ds_read bf; 2 MFMA}.
#define GITER(ks, TOPW, DOISSUE)                                         \
  do {                                                                   \
    asm volatile("s_waitcnt vmcnt(" TOPW ")" ::: "memory");              \
    __builtin_amdgcn_s_barrier();                                        \
    v4i af0, af1;                                                        \
    af0.x = (int)pack4(q[(ks) & 1][0]);                                  \
    af0.y = (int)pack4(q[(ks) & 1][1]);                                  \
    af0.z = (int)pack4(q[(ks) & 1][2]);                                  \
    af0.w = (int)pack4(q[(ks) & 1][3]);                                  \
    af1.x = (int)pack4(q[(ks) & 1][4]);                                  \
    af1.y = (int)pack4(q[(ks) & 1][5]);                                  \
    af1.z = (int)pack4(q[(ks) & 1][6]);                                  \
    af1.w = (int)pack4(q[(ks) & 1][7]);                                  \
    if (DOISSUE) { ISSUE_A((ks) + 2); ISSUE_B((ks) + 2); }               \
    const signed char* _bb = &Bbuf[(ks) % 3][brd];                       \
    _Pragma("unroll") for (int n = 0; n < 8; ++n) {                      \
      v4i bf = *(const v4i*)(_bb + n * 1024);                            \
      acc[0][n] = __builtin_amdgcn_mfma_i32_16x16x64_i8(af0, bf,         \
                                                        acc[0][n], 0, 0, 0); \
      acc[1][n] = __builtin_amdgcn_mfma_i32_16x16x64_i8(af1, bf,         \
                                                        acc[1][n], 0, 0, 0); \
    }                                                                    \
  } while (0)

  // Prologue: stages 0 and 1 in flight (20 vmem ops).
  ISSUE_A(0); ISSUE_B(0);
  ISSUE_A(1); ISSUE_B(1);

  GITER(0, "10", 1);
  GITER(1, "10", 1);
  GITER(2, "10", 1);
  GITER(3, "10", 1);
  GITER(4, "10", 1);
  GITER(5, "10", 1);
  GITER(6, "10", 1);
  GITER(7, "10", 1);
  GITER(8, "10", 1);
  GITER(9, "10", 1);   // issues stage 11 (last)
  GITER(10, "10", 0);  // outstanding 10,11 -> drain 10
  GITER(11, "0", 0);

  // Epilogue: C/D layout col = lane&15, row = (lane>>4)*4 + reg. Output int32.
  const float alpha = *alpha_p;
  float bv[8];
#pragma unroll
  for (int n = 0; n < 8; ++n) bv[n] = bias[col0 + n * 16 + fr];

#pragma unroll
  for (int m = 0; m < 2; ++m) {
    int orow = row0 + wv * 32 + m * 16 + fg * 4;
#pragma unroll
    for (int n = 0; n < 8; ++n) {
      int ocol = col0 + n * 16 + fr;
      int* po = out + orow * N_TOT + ocol;
#pragma unroll
      for (int r = 0; r < 4; ++r) {
        float v = rintf((float)acc[m][n][r] * alpha + bv[n]);
        v = fminf(127.f, fmaxf(-128.f, v));
        po[r * N_TOT] = (int)v;
      }
    }
  }
}

extern "C" void kernel_launch(void* const* d_in, const int* in_sizes, int n_in,
                              void* d_out, int out_size, void* d_ws, size_t ws_size,
                              hipStream_t stream) {
  const int* X = (const int*)d_in[0];        // [4,8192,768] int8 promoted to int32
  const int* W = (const int*)d_in[1];        // [768,768] int8 promoted to int32
  const float* bias = (const float*)d_in[2]; // [1,768] fp16 promoted to float32
  const float* alpha = (const float*)d_in[3];
  int* out = (int*)d_out;                    // int8 output promoted to int32
  signed char* W8T = (signed char*)d_ws;     // 768*768 = 589,824 B scratch

  dim3 pg(K_TOT / 64, N_TOT / 64);
  pack_w_kernel<<<pg, 256, 0, stream>>>(W, W8T);
  gemm_i8_kernel<<<(M_TOT / 128) * (N_TOT / 128), 256, 0, stream>>>(X, W8T, bias, alpha, out);
}

// Round 10
// 64.265 us; speedup vs baseline: 2.4041x; 1.4514x over previous
//
#include <hip/hip_runtime.h>

#define M_TOT 32768
#define K_TOT 768
#define N_TOT 768

typedef int v4i __attribute__((ext_vector_type(4)));
typedef unsigned int v4u __attribute__((ext_vector_type(4)));

#define GLOAD_LDS(g, l) __builtin_amdgcn_global_load_lds( \
    (const __attribute__((address_space(1))) unsigned int*)(g), \
    (__attribute__((address_space(3))) unsigned int*)(l), 16, 0, 0)

// Pack 4 int32 (each holding an int8 value) into one dword of 4 bytes. (verified R2)
__device__ __forceinline__ unsigned pack4(v4i a) {
  unsigned lo = __builtin_amdgcn_perm((unsigned)a.y, (unsigned)a.x, 0x00000400u);
  unsigned hi = __builtin_amdgcn_perm((unsigned)a.w, (unsigned)a.z, 0x00000400u);
  return __builtin_amdgcn_perm(hi, lo, 0x05040100u);
}

// W[k][n] int32 -> W8T[n][k] int8 (transposed, packed)
__global__ __launch_bounds__(256) void pack_w_kernel(const int* __restrict__ W,
                                                     signed char* __restrict__ W8T) {
  __shared__ signed char t[64][72];
  const int k0 = blockIdx.x * 64, n0 = blockIdx.y * 64;
  for (int i = threadIdx.x; i < 4096; i += 256) {
    int k = i >> 6, n = i & 63;
    t[n][k] = (signed char)W[(k0 + k) * N_TOT + n0 + n];
  }
  __syncthreads();
  for (int i = threadIdx.x; i < 4096; i += 256) {
    int n = i >> 6, k = i & 63;
    W8T[(n0 + n) * K_TOT + k0 + k] = t[n][k];
  }
}

// out_i32 = clamp(round((X@W)*alpha + bias))
// R4 structure (proven 55us) with ONE change: BN 128->256.
// BM=128, BN=256, BK=64; 512 thr = 8 waves (2M x 4N), wave tile 64x64 (= R4).
// X re-read factor drops 6->3 (L2/L3 X traffic ~halved); barrier events per
// CU halve (768 blocks, 128 MFMA/barrier).
// Pipeline: depth-2 counted vmcnt (R4 schedule). Stage = 4 A global_dwordx4
// + 2 B global_load_lds, A issued before B. Exact FIFO ledger:
//   prologue wait vmcnt(8)  [drain A(0), leave B0,A1,B1]
//   steady   TOP  vmcnt(6)  [drain B(k), leave A(k+1),B(k+1)]
//            MID  vmcnt(8)  [drain A(k+1), leave B(k+1),A(k+2),B(k+2)]
//   ks=10 MID vmcnt(2); ks=11 TOP vmcnt(0).
__global__ __launch_bounds__(512, 3) void gemm_i8_kernel(
    const int* __restrict__ X, const signed char* __restrict__ W8T,
    const float* __restrict__ bias, const float* __restrict__ alpha_p,
    int* __restrict__ out) {
  __shared__ __align__(16) signed char Abuf[2][8192];
  __shared__ __align__(16) signed char Bbuf[3][16384];

  // Bijective XCD-chunked swizzle: 768 wgs = 8 XCDs x 96; nt fast so the 3
  // sibling N-tiles of one X M-panel run concurrently on one XCD's L2.
  const int d = blockIdx.x;
  const int t = (d & 7) * 96 + (d >> 3);
  const int mt = t / 3, nt = t - mt * 3;
  const int row0 = mt << 7, col0 = nt << 8;

  const int tid = threadIdx.x;
  const int lane = tid & 63;
  const int wave = tid >> 6;              // 0..7
  const int wr = wave >> 2, wc = wave & 3;
  const int fr = lane & 15, fg = lane >> 4;
  const int fsw = (fr & 3) << 4;          // frag-read XOR swizzle (row&3==fr&3)

  // A loads: thread owns row arow = tid>>2 (0..127), 16 consecutive int32 at
  // col (tid&3)*16 -> 4 dwordx4, pack -> 16 int8 bytes -> ONE ds_write_b128.
  const int arow = tid >> 2;
  const int acb = (tid & 3) << 4;         // byte/int32-col base within 64
  const int* Xbase = X + (row0 + arow) * K_TOT + (acb);
  const int aoff = arow * 64 + (acb ^ ((arow & 3) << 4));

  // B gloads: chunk c = i*512 + tid: row r = c>>2 (0..255), 16B slot (c&3);
  // source pre-swizzled so linear LDS dest + swizzled frag read agree.
  int bsrc[2], bdst[2];
#pragma unroll
  for (int i = 0; i < 2; ++i) {
    int c = i * 512 + tid;
    int r = c >> 2, s = (c & 3) << 4;
    bsrc[i] = (col0 + r) * K_TOT + (s ^ ((r & 3) << 4));
    bdst[i] = i * 8192 + wave * 1024;     // wave-uniform base; HW adds lane*16
  }

  v4i q[2][4];
  const v4i zero = {0, 0, 0, 0};
  v4i acc[4][4];
#pragma unroll
  for (int m = 0; m < 4; ++m)
#pragma unroll
    for (int n = 0; n < 4; ++n) acc[m][n] = zero;

#define ISSUE_A(ks)                                                      \
  do {                                                                   \
    const int* _p = Xbase + (ks) * 64;                                   \
    _Pragma("unroll") for (int j = 0; j < 4; ++j)                        \
        q[(ks) & 1][j] = *(const v4i*)(_p + j * 4);                      \
  } while (0)

#define ISSUE_B(ks)                                                      \
  do {                                                                   \
    const signed char* _w = W8T + (ks) * 64;                             \
    signed char* _lb = Bbuf[(ks) % 3];                                   \
    GLOAD_LDS(_w + bsrc[0], _lb + bdst[0]);                              \
    GLOAD_LDS(_w + bsrc[1], _lb + bdst[1]);                              \
  } while (0)

#define PACK_WRITE_A(tt)                                                 \
  do {                                                                   \
    unsigned _pk[4];                                                     \
    _Pragma("unroll") for (int j = 0; j < 4; ++j)                        \
        _pk[j] = pack4(q[(tt) & 1][j]);                                  \
    v4u _w = {_pk[0], _pk[1], _pk[2], _pk[3]};                           \
    *(v4u*)&Abuf[(tt) & 1][aoff] = _w;                                   \
  } while (0)

#define FRAGS_MFMA(ks)                                                   \
  do {                                                                   \
    v4i af[4], bf[4];                                                    \
    const signed char* _ab = Abuf[(ks) & 1];                             \
    const signed char* _bb = Bbuf[(ks) % 3];                             \
    const int _kb = (fg << 4) ^ fsw;                                     \
    _Pragma("unroll") for (int m = 0; m < 4; ++m)                        \
        af[m] = *(const v4i*)&_ab[(wr * 64 + m * 16 + fr) * 64 + _kb];   \
    _Pragma("unroll") for (int n = 0; n < 4; ++n)                        \
        bf[n] = *(const v4i*)&_bb[(wc * 64 + n * 16 + fr) * 64 + _kb];   \
    __builtin_amdgcn_s_setprio(1);                                       \
    _Pragma("unroll") for (int m = 0; m < 4; ++m)                        \
        _Pragma("unroll") for (int n = 0; n < 4; ++n)                    \
            acc[m][n] = __builtin_amdgcn_mfma_i32_16x16x64_i8(           \
                af[m], bf[n], acc[m][n], 0, 0, 0);                       \
    __builtin_amdgcn_s_setprio(0);                                       \
  } while (0)

  // GITER (R4 schedule): top-wait (drain B(ks); lgkm for all ds_writes) ->
  // barrier -> issue A(ks+2),B(ks+2) -> frags+MFMA(ks) -> mid-wait (drain
  // A(ks+1) regs) -> pack+ds_write.
#define GITER(ks, TOPW, MIDW)                                            \
  do {                                                                   \
    asm volatile("s_waitcnt vmcnt(" TOPW ") lgkmcnt(0)" ::: "memory");   \
    __builtin_amdgcn_s_barrier();                                        \
    if ((ks) + 2 < 12) { ISSUE_A((ks) + 2); ISSUE_B((ks) + 2); }         \
    FRAGS_MFMA(ks);                                                      \
    if ((ks) + 1 < 12) {                                                 \
      asm volatile("s_waitcnt vmcnt(" MIDW ")" ::: "memory");            \
      PACK_WRITE_A((ks) + 1);                                            \
    }                                                                    \
  } while (0)

  // Prologue: stages 0,1 in flight: [A0x4, B0x2, A1x4, B1x2].
  ISSUE_A(0); ISSUE_B(0);
  ISSUE_A(1); ISSUE_B(1);
  asm volatile("s_waitcnt vmcnt(8)" ::: "memory");  // drain A(0)
  PACK_WRITE_A(0);

  GITER(0, "6", "8");
  GITER(1, "6", "8");
  GITER(2, "6", "8");
  GITER(3, "6", "8");
  GITER(4, "6", "8");
  GITER(5, "6", "8");
  GITER(6, "6", "8");
  GITER(7, "6", "8");
  GITER(8, "6", "8");
  GITER(9, "6", "8");
  GITER(10, "6", "2");
  GITER(11, "0", "0");

  // Epilogue: C/D layout col = lane&15, row = (lane>>4)*4 + reg. Output int32.
  const float alpha = *alpha_p;
  float bv[4];
#pragma unroll
  for (int n = 0; n < 4; ++n) bv[n] = bias[col0 + wc * 64 + n * 16 + fr];

#pragma unroll
  for (int m = 0; m < 4; ++m) {
    int orow = row0 + wr * 64 + m * 16 + fg * 4;
#pragma unroll
    for (int n = 0; n < 4; ++n) {
      int ocol = col0 + wc * 64 + n * 16 + fr;
      int* po = out + orow * N_TOT + ocol;
#pragma unroll
      for (int r = 0; r < 4; ++r) {
        float v = rintf((float)acc[m][n][r] * alpha + bv[n]);
        v = fminf(127.f, fmaxf(-128.f, v));
        po[r * N_TOT] = (int)v;
      }
    }
  }
}

extern "C" void kernel_launch(void* const* d_in, const int* in_sizes, int n_in,
                              void* d_out, int out_size, void* d_ws, size_t ws_size,
                              hipStream_t stream) {
  const int* X = (const int*)d_in[0];        // [4,8192,768] int8 promoted to int32
  const int* W = (const int*)d_in[1];        // [768,768] int8 promoted to int32
  const float* bias = (const float*)d_in[2]; // [1,768] fp16 promoted to float32
  const float* alpha = (const float*)d_in[3];
  int* out = (int*)d_out;                    // int8 output promoted to int32
  signed char* W8T = (signed char*)d_ws;     // 768*768 = 589,824 B scratch

  dim3 pg(K_TOT / 64, N_TOT / 64);
  pack_w_kernel<<<pg, 256, 0, stream>>>(W, W8T);
  gemm_i8_kernel<<<(M_TOT / 128) * (N_TOT / 256), 512, 0, stream>>>(X, W8T, bias, alpha, out);
}

// Round 11
// 61.361 us; speedup vs baseline: 2.5179x; 1.0473x over previous
//
#include <hip/hip_runtime.h>

#define M_TOT 32768
#define K_TOT 768
#define N_TOT 768

typedef int v4i __attribute__((ext_vector_type(4)));

#define GLOAD_LDS(g, l) __builtin_amdgcn_global_load_lds( \
    (const __attribute__((address_space(1))) unsigned int*)(g), \
    (__attribute__((address_space(3))) unsigned int*)(l), 16, 0, 0)

// Pack 4 int32 (each holding an int8 value) into one dword of 4 bytes. (verified R2)
__device__ __forceinline__ unsigned pack4(v4i a) {
  unsigned lo = __builtin_amdgcn_perm((unsigned)a.y, (unsigned)a.x, 0x00000400u);
  unsigned hi = __builtin_amdgcn_perm((unsigned)a.w, (unsigned)a.z, 0x00000400u);
  return __builtin_amdgcn_perm(hi, lo, 0x05040100u);
}

// W[k][n] int32 -> W8T[n][k] int8 (transposed, packed)
__global__ __launch_bounds__(256) void pack_w_kernel(const int* __restrict__ W,
                                                     signed char* __restrict__ W8T) {
  __shared__ signed char t[64][72];
  const int k0 = blockIdx.x * 64, n0 = blockIdx.y * 64;
  for (int i = threadIdx.x; i < 4096; i += 256) {
    int k = i >> 6, n = i & 63;
    t[n][k] = (signed char)W[(k0 + k) * N_TOT + n0 + n];
  }
  __syncthreads();
  for (int i = threadIdx.x; i < 4096; i += 256) {
    int n = i >> 6, k = i & 63;
    W8T[(n0 + n) * K_TOT + k0 + k] = t[n][k];
  }
}

// out_i32 = clamp(round((X@W)*alpha + bias))
// R4 (proven 55us) + ONE change: A global->reg cover deepened 1.3 -> 2.3
// iters via q[3][8] ring (issue A(k+3) at mid of iter k into the slot freed
// by packing A(k+1)). B path / tile / waves / grid / swizzles unchanged.
// BM=128, BN=128, BK=64; 4 waves (2x2), wave 64x64 via 4x4 mfma_i32_16x16x64.
// FIFO ledger (per iter issues: B(k+2)x2 at top, A(k+3)x8 at mid):
//   steady entering-top queue [B(k)2, A(k+1)8, B(k+1)2, A(k+2)8] = 20
//     TOP vmcnt(18)  -> drains B(k)
//     after B(k+2) issue: [A(k+1)8, B(k+1)2, A(k+2)8, B(k+2)2] = 20
//     MID vmcnt(12)  -> drains A(k+1) exactly
//   tails: ks=10 TOP=10 MID=2; ks=11 TOP=0. Prologue drain A(0): vmcnt(20).
__global__ __launch_bounds__(256, 2) void gemm_i8_kernel(
    const int* __restrict__ X, const signed char* __restrict__ W8T,
    const float* __restrict__ bias, const float* __restrict__ alpha_p,
    int* __restrict__ out) {
  __shared__ __align__(16) signed char Abuf[2][8192];
  __shared__ __align__(16) signed char Bbuf[3][8192];

  // Bijective XCD-chunked swizzle: 1536 wgs = 8 XCDs x 192; nt fast so the 6
  // sibling N-tiles of one X M-panel share that XCD's L2.
  const int d = blockIdx.x;
  const int t = (d & 7) * 192 + (d >> 3);
  const int mt = t / 6, nt = t - mt * 6;
  const int row0 = mt << 7, col0 = nt << 7;

  const int tid = threadIdx.x;
  const int lane = tid & 63;
  const int wave = tid >> 6;
  const int wr = wave >> 1, wc = wave & 1;
  const int fr = lane & 15, fg = lane >> 4;
  const int fsw = (fr & 3) << 4;          // frag-read XOR swizzle

  // A loads: chunk j covers row rA = 16*j + (tid>>4), int-cols (tid&15)*4..+4
  // => each dwordx4 instr is a fully-coalesced 1KB wave access.
  const int arow = tid >> 4;              // 0..15
  const int acol = (tid & 15) << 2;       // int col within 64-int stage
  const int* Xbase = X + (row0 + arow) * K_TOT + acol;
  const int awsw = (arow & 3) << 4;       // (16j+arow)&3 == arow&3

  // B gloads: chunk c = i*256+tid: row rB=c>>2, slot s=(c&3)*16; source
  // pre-swizzled so linear LDS + swizzled read agree (rule #21).
  int bsrc[2], bdst[2];
#pragma unroll
  for (int i = 0; i < 2; ++i) {
    int c = i * 256 + tid;
    int r = c >> 2, s = (c & 3) << 4;
    bsrc[i] = (col0 + r) * K_TOT + (s ^ ((r & 3) << 4));
    bdst[i] = i * 4096 + wave * 1024;     // wave-uniform base; HW adds lane*16
  }

  v4i q[3][8];
  const v4i zero = {0, 0, 0, 0};
  v4i acc[4][4];
#pragma unroll
  for (int m = 0; m < 4; ++m)
#pragma unroll
    for (int n = 0; n < 4; ++n) acc[m][n] = zero;

#define ISSUE_A(ks)                                                      \
  do {                                                                   \
    const int* _p = Xbase + (ks) * 64;                                   \
    _Pragma("unroll") for (int j = 0; j < 8; ++j)                        \
        q[(ks) % 3][j] = *(const v4i*)(_p + j * 16 * K_TOT);             \
  } while (0)

#define ISSUE_B(ks)                                                      \
  do {                                                                   \
    const signed char* _w = W8T + (ks) * 64;                             \
    signed char* _lb = Bbuf[(ks) % 3];                                   \
    GLOAD_LDS(_w + bsrc[0], _lb + bdst[0]);                              \
    GLOAD_LDS(_w + bsrc[1], _lb + bdst[1]);                              \
  } while (0)

#define PACK_WRITE_A(tt)                                                 \
  do {                                                                   \
    signed char* _ab = Abuf[(tt) & 1];                                   \
    _Pragma("unroll") for (int j = 0; j < 8; ++j) {                      \
      unsigned _dw = pack4(q[(tt) % 3][j]);                              \
      *(unsigned*)&_ab[(16 * j + arow) * 64 + (acol ^ awsw)] = _dw;      \
    }                                                                    \
  } while (0)

#define FRAGS_MFMA(ks)                                                   \
  do {                                                                   \
    v4i af[4], bf[4];                                                    \
    const signed char* _ab = Abuf[(ks) & 1];                             \
    const signed char* _bb = Bbuf[(ks) % 3];                             \
    const int _kb = (fg << 4) ^ fsw;                                     \
    _Pragma("unroll") for (int m = 0; m < 4; ++m)                        \
        af[m] = *(const v4i*)&_ab[(wr * 64 + m * 16 + fr) * 64 + _kb];   \
    _Pragma("unroll") for (int n = 0; n < 4; ++n)                        \
        bf[n] = *(const v4i*)&_bb[(wc * 64 + n * 16 + fr) * 64 + _kb];   \
    __builtin_amdgcn_s_setprio(1);                                       \
    _Pragma("unroll") for (int m = 0; m < 4; ++m)                        \
        _Pragma("unroll") for (int n = 0; n < 4; ++n)                    \
            acc[m][n] = __builtin_amdgcn_mfma_i32_16x16x64_i8(           \
                af[m], bf[n], acc[m][n], 0, 0, 0);                       \
    __builtin_amdgcn_s_setprio(0);                                       \
  } while (0)

  // GITER: top-wait (drain B(ks); all ds_writes via lgkm) -> barrier ->
  // issue B(ks+2) -> frags+MFMA(ks) -> mid-wait (drain A(ks+1) regs,
  // 2.3-iter-old) -> pack+ds_write A(ks+1) -> issue A(ks+3) into freed slot.
#define GITER(ks, TOPW, MIDW)                                            \
  do {                                                                   \
    asm volatile("s_waitcnt vmcnt(" TOPW ") lgkmcnt(0)" ::: "memory");   \
    __builtin_amdgcn_s_barrier();                                        \
    if ((ks) + 2 < 12) ISSUE_B((ks) + 2);                                \
    FRAGS_MFMA(ks);                                                      \
    if ((ks) + 1 < 12) {                                                 \
      asm volatile("s_waitcnt vmcnt(" MIDW ")" ::: "memory");            \
      PACK_WRITE_A((ks) + 1);                                            \
      if ((ks) + 3 < 12) ISSUE_A((ks) + 3);                              \
    }                                                                    \
  } while (0)

  // Prologue: A0,B0,A1,B1,A2 in flight (28 ops); drain A0 (leave 20 =
  // [B0,A1,B1,A2], the steady entering-top queue); pack A0.
  ISSUE_A(0); ISSUE_B(0);
  ISSUE_A(1); ISSUE_B(1);
  ISSUE_A(2);
  asm volatile("s_waitcnt vmcnt(20)" ::: "memory");
  PACK_WRITE_A(0);

  GITER(0, "18", "12");
  GITER(1, "18", "12");
  GITER(2, "18", "12");
  GITER(3, "18", "12");
  GITER(4, "18", "12");
  GITER(5, "18", "12");
  GITER(6, "18", "12");
  GITER(7, "18", "12");
  GITER(8, "18", "12");
  GITER(9, "18", "12");   // issues B(11); A(12) skipped
  GITER(10, "10", "2");   // entering [B10,A11,B11]; drain B10; mid leaves B11
  GITER(11, "0", "0");

  // Epilogue: C/D layout col = lane&15, row = (lane>>4)*4 + reg. Output int32.
  const float alpha = *alpha_p;
  float bv[4];
#pragma unroll
  for (int n = 0; n < 4; ++n) bv[n] = bias[col0 + wc * 64 + n * 16 + fr];

#pragma unroll
  for (int m = 0; m < 4; ++m) {
    int orow = row0 + wr * 64 + m * 16 + fg * 4;
#pragma unroll
    for (int n = 0; n < 4; ++n) {
      int ocol = col0 + wc * 64 + n * 16 + fr;
      int* po = out + orow * N_TOT + ocol;
#pragma unroll
      for (int r = 0; r < 4; ++r) {
        float v = rintf((float)acc[m][n][r] * alpha + bv[n]);
        v = fminf(127.f, fmaxf(-128.f, v));
        po[r * N_TOT] = (int)v;
      }
    }
  }
}

extern "C" void kernel_launch(void* const* d_in, const int* in_sizes, int n_in,
                              void* d_out, int out_size, void* d_ws, size_t ws_size,
                              hipStream_t stream) {
  const int* X = (const int*)d_in[0];        // [4,8192,768] int8 promoted to int32
  const int* W = (const int*)d_in[1];        // [768,768] int8 promoted to int32
  const float* bias = (const float*)d_in[2]; // [1,768] fp16 promoted to float32
  const float* alpha = (const float*)d_in[3];
  int* out = (int*)d_out;                    // int8 output promoted to int32
  signed char* W8T = (signed char*)d_ws;     // 768*768 = 589,824 B scratch

  dim3 pg(K_TOT / 64, N_TOT / 64);
  pack_w_kernel<<<pg, 256, 0, stream>>>(W, W8T);
  gemm_i8_kernel<<<(M_TOT / 128) * (N_TOT / 128), 256, 0, stream>>>(X, W8T, bias, alpha, out);
}